// Round 3
// baseline (457.526 us; speedup 1.0000x reference)
//
#include <hip/hip_runtime.h>

#define TT 512
#define FF 8
#define CC 16
#define HH 10

__device__ __forceinline__ float sigf(float z){
    return __builtin_amdgcn_rcpf(1.f + __expf(-z));
}
__device__ __forceinline__ float tanh_f(float z){
    return 1.f - 2.f * __builtin_amdgcn_rcpf(1.f + __expf(2.f * z));
}

// 32 lanes per batch element: lane = bsub*32 + p*16 + j
//   j = lane & 15 : channel (conv) / hidden unit (j<10)
//   p = (lane>>4)&1 : gate half. p=0 owns gates {i,f}, p=1 owns {g,o} (as float2)
// All weights in registers. h/c state replicated in both p-halves (identical ops
// -> bitwise identical). Broadcasts are width-16 shfls; cross-p exchange is
// shfl_xor(16, width 32).
__global__ __launch_bounds__(64, 1)
void lstm_fused(const float* __restrict__ x,
                const float* __restrict__ conv_w, const float* __restrict__ conv_b,
                const float* __restrict__ w_ih1,  const float* __restrict__ w_hh1,
                const float* __restrict__ b_ih1,  const float* __restrict__ b_hh1,
                const float* __restrict__ w_ih2,  const float* __restrict__ w_hh2,
                const float* __restrict__ b_ih2,  const float* __restrict__ b_hh2,
                const float* __restrict__ lin_w,  const float* __restrict__ lin_b,
                float* __restrict__ out)
{
    const int lane  = threadIdx.x;
    const int bsub  = lane >> 5;           // 0..1
    const int g5    = lane & 31;
    const int p     = g5 >> 4;             // gate half
    const int j     = g5 & 15;             // channel / hidden unit
    const int batch = blockIdx.x * 2 + bsub;
    const int jj    = (j < HH) ? j : (HH - 1);

    // this lane's two gate rows: p=0 -> {i,f} rows jj, jj+10 ; p=1 -> {g,o} rows jj+20, jj+30
    const int r0 = jj + p * 20;
    const int r1 = jj + 10 + p * 20;

    // ---- loop-invariant weights in registers ----
    // conv: channel j, feature half p (f = p*4 .. p*4+3), 3 taps each
    float cw[12];
    #pragma unroll
    for (int m = 0; m < 12; ++m) cw[m] = conv_w[j*24 + p*12 + m];
    const float cb = conv_b[j];

    float2 wih1_r[CC], whh1_r[HH], wih2_r[HH], whh2_r[HH];
    #pragma unroll
    for (int k = 0; k < CC; ++k)
        wih1_r[k] = make_float2(w_ih1[r0*CC + k], w_ih1[r1*CC + k]);
    #pragma unroll
    for (int k = 0; k < HH; ++k){
        whh1_r[k] = make_float2(w_hh1[r0*HH + k], w_hh1[r1*HH + k]);
        wih2_r[k] = make_float2(w_ih2[r0*HH + k], w_ih2[r1*HH + k]);
        whh2_r[k] = make_float2(w_hh2[r0*HH + k], w_hh2[r1*HH + k]);
    }
    const float2 b1q = make_float2(b_ih1[r0] + b_hh1[r0], b_ih1[r1] + b_hh1[r1]);
    const float2 b2q = make_float2(b_ih2[r0] + b_hh2[r0], b_ih2[r1] + b_hh2[r1]);

    const float* xb = x + (size_t)batch * (TT*FF) + p*4;   // this lane's 4-col slice

    // sliding window: 3 rows x 4 cols (this lane's feature half)
    float4 w0 = make_float4(0.f,0.f,0.f,0.f);
    float4 w1 = *(const float4*)(xb + 0*FF);
    float4 w2 = *(const float4*)(xb + 1*FF);

    float h1 = 0.f, c1 = 0.f, h2 = 0.f, c2 = 0.f;

    #pragma unroll 1
    for (int t = 0; t < TT; ++t){
        // prefetch row t+2
        float4 nx = make_float4(0.f,0.f,0.f,0.f);
        if (t + 2 < TT) nx = *(const float4*)(xb + (t+2)*FF);

        // ---- conv1d half-channel partial, then cross-p combine ----
        float acc = 0.f;
        acc = fmaf(w0.x, cw[0], acc);  acc = fmaf(w1.x, cw[1], acc);  acc = fmaf(w2.x, cw[2], acc);
        acc = fmaf(w0.y, cw[3], acc);  acc = fmaf(w1.y, cw[4], acc);  acc = fmaf(w2.y, cw[5], acc);
        acc = fmaf(w0.z, cw[6], acc);  acc = fmaf(w1.z, cw[7], acc);  acc = fmaf(w2.z, cw[8], acc);
        acc = fmaf(w0.w, cw[9], acc);  acc = fmaf(w1.w, cw[10], acc); acc = fmaf(w2.w, cw[11], acc);
        acc += __shfl_xor(acc, 16, 32);          // combine feature halves
        const float y = fmaxf(acc + cb, 0.f);    // channel j, in both p-halves

        // ---- layer 1: this lane's float2 gate pair ----
        float2 a0 = b1q, a1 = make_float2(0.f, 0.f);   // dual partials -> 4 indep chains
        #pragma unroll
        for (int k = 0; k < CC; k += 2){
            const float y0 = __shfl(y, k,   16);
            const float y1 = __shfl(y, k+1, 16);
            a0.x = fmaf(y0, wih1_r[k  ].x, a0.x); a0.y = fmaf(y0, wih1_r[k  ].y, a0.y);
            a1.x = fmaf(y1, wih1_r[k+1].x, a1.x); a1.y = fmaf(y1, wih1_r[k+1].y, a1.y);
        }
        #pragma unroll
        for (int k = 0; k < HH; k += 2){
            const float h0 = __shfl(h1, k, 16);
            const float hb = (k+1 < HH) ? __shfl(h1, k+1, 16) : 0.f;
            a0.x = fmaf(h0, whh1_r[k].x, a0.x); a0.y = fmaf(h0, whh1_r[k].y, a0.y);
            if (k+1 < HH){ a1.x = fmaf(hb, whh1_r[k+1].x, a1.x); a1.y = fmaf(hb, whh1_r[k+1].y, a1.y); }
        }
        const float2 g1 = make_float2(a0.x + a1.x, a0.y + a1.y);

        // activations: p=0 computes sig(i),sig(f); p=1 computes tanh(g),sig(o)
        float2 mine;
        mine.x = p ? tanh_f(g1.x) : sigf(g1.x);
        mine.y = sigf(g1.y);
        float2 other;
        other.x = __shfl_xor(mine.x, 16, 32);
        other.y = __shfl_xor(mine.y, 16, 32);
        {
            const float si = p ? other.x : mine.x;
            const float sf = p ? other.y : mine.y;
            const float tg = p ? mine.x  : other.x;
            const float so = p ? mine.y  : other.y;
            c1 = fmaf(sf, c1, si * tg);
            h1 = so * tanh_f(c1);
        }

        // ---- layer 2 ----
        float2 d0 = b2q, d1 = make_float2(0.f, 0.f);
        #pragma unroll
        for (int k = 0; k < HH; k += 2){
            const float ha = __shfl(h1, k, 16);
            const float hb = (k+1 < HH) ? __shfl(h1, k+1, 16) : 0.f;
            d0.x = fmaf(ha, wih2_r[k].x, d0.x); d0.y = fmaf(ha, wih2_r[k].y, d0.y);
            if (k+1 < HH){ d1.x = fmaf(hb, wih2_r[k+1].x, d1.x); d1.y = fmaf(hb, wih2_r[k+1].y, d1.y); }
        }
        #pragma unroll
        for (int k = 0; k < HH; k += 2){
            const float ha = __shfl(h2, k, 16);
            const float hb = (k+1 < HH) ? __shfl(h2, k+1, 16) : 0.f;
            d0.x = fmaf(ha, whh2_r[k].x, d0.x); d0.y = fmaf(ha, whh2_r[k].y, d0.y);
            if (k+1 < HH){ d1.x = fmaf(hb, whh2_r[k+1].x, d1.x); d1.y = fmaf(hb, whh2_r[k+1].y, d1.y); }
        }
        const float2 g2 = make_float2(d0.x + d1.x, d0.y + d1.y);

        float2 mine2;
        mine2.x = p ? tanh_f(g2.x) : sigf(g2.x);
        mine2.y = sigf(g2.y);
        float2 other2;
        other2.x = __shfl_xor(mine2.x, 16, 32);
        other2.y = __shfl_xor(mine2.y, 16, 32);
        {
            const float si = p ? other2.x : mine2.x;
            const float sf = p ? other2.y : mine2.y;
            const float tg = p ? mine2.x  : other2.x;
            const float so = p ? mine2.y  : other2.y;
            c2 = fmaf(sf, c2, si * tg);
            h2 = so * tanh_f(c2);
        }

        // slide window
        w0 = w1; w1 = w2; w2 = nx;
    }

    // final: sigmoid(h2 . lin_w + lin_b); h2_j replicated in both halves,
    // reduce the 10 active j-lanes within this 16-halfgroup
    float part = (j < HH) ? h2 * lin_w[jj] : 0.f;
    #pragma unroll
    for (int off = 8; off > 0; off >>= 1) part += __shfl_xor(part, off, 16);
    if (g5 == 0) out[batch] = sigf(part + lin_b[0]);
}

extern "C" void kernel_launch(void* const* d_in, const int* in_sizes, int n_in,
                              void* d_out, int out_size, void* d_ws, size_t ws_size,
                              hipStream_t stream) {
    const float* x      = (const float*)d_in[0];
    const float* conv_w = (const float*)d_in[1];
    const float* conv_b = (const float*)d_in[2];
    const float* w_ih1  = (const float*)d_in[3];
    const float* w_hh1  = (const float*)d_in[4];
    const float* b_ih1  = (const float*)d_in[5];
    const float* b_hh1  = (const float*)d_in[6];
    const float* w_ih2  = (const float*)d_in[7];
    const float* w_hh2  = (const float*)d_in[8];
    const float* b_ih2  = (const float*)d_in[9];
    const float* b_hh2  = (const float*)d_in[10];
    const float* lin_w  = (const float*)d_in[11];
    const float* lin_b  = (const float*)d_in[12];
    float* out = (float*)d_out;

    // 2048 batches * 32 lanes = 65536 threads = 1024 waves -> 1 wave per SIMD chip-wide
    lstm_fused<<<dim3(1024), dim3(64), 0, stream>>>(
        x, conv_w, conv_b, w_ih1, w_hh1, b_ih1, b_hh1,
        w_ih2, w_hh2, b_ih2, b_hh2, lin_w, lin_b, out);
}

// Round 4
// 339.649 us; speedup vs baseline: 1.3471x; 1.3471x over previous
//
#include <hip/hip_runtime.h>

#define TT 512
#define FF 8
#define CC 16
#define HH 10

__device__ __forceinline__ float rl(float v, int k){
    // wave-uniform broadcast: lane k -> SGPR, folds as scalar operand into v_fma
    return __int_as_float(__builtin_amdgcn_readlane(__float_as_int(v), k));
}
__device__ __forceinline__ float sigf(float z){
    return __builtin_amdgcn_rcpf(1.f + __expf(-z));
}
__device__ __forceinline__ float tanh_f(float z){
    return 1.f - 2.f * __builtin_amdgcn_rcpf(1.f + __expf(2.f * z));
}

// ONE wave (64 lanes) per batch element. 2048 waves -> 2 waves/SIMD chip-wide.
//   lane < 40 : owns gate row `grow` = q*10+u (q: 0=i,1=f,2=g,3=o ; u: hidden unit)
//   lane & 15 : conv channel (y valid in lanes 0..15, read via readlane)
// All broadcasts of y/h1/h2 are v_readlane (wave-uniform k) -> SGPR operands.
// Gate activations computed 1-per-lane (branchless sig/tanh select), then
// collected per-unit with 4 bpermutes; h/c state ends up replicated in all
// lanes (identical inputs -> identical results), so next step's readlanes of
// lanes 0..9 are valid.
__global__ __launch_bounds__(64, 2)
void lstm_fused(const float* __restrict__ x,
                const float* __restrict__ conv_w, const float* __restrict__ conv_b,
                const float* __restrict__ w_ih1,  const float* __restrict__ w_hh1,
                const float* __restrict__ b_ih1,  const float* __restrict__ b_hh1,
                const float* __restrict__ w_ih2,  const float* __restrict__ w_hh2,
                const float* __restrict__ b_ih2,  const float* __restrict__ b_hh2,
                const float* __restrict__ lin_w,  const float* __restrict__ lin_b,
                float* __restrict__ out)
{
    const int lane  = threadIdx.x;
    const int batch = blockIdx.x;
    const int grow  = (lane < 40) ? lane : 39;      // gate row 0..39
    const int q     = grow / 10;                    // gate type 0=i,1=f,2=g,3=o
    const int u     = grow - q * 10;                // hidden unit 0..9
    const int ch    = lane & 15;                    // conv channel
    const bool isG  = (q == 2);

    // ---- loop-invariant weights in registers ----
    float cw[24];
    #pragma unroll
    for (int m = 0; m < 24; ++m) cw[m] = conv_w[ch*24 + m];
    const float cb = conv_b[ch];

    float wih1[CC], whh1[HH], wih2[HH], whh2[HH];
    #pragma unroll
    for (int k = 0; k < CC; ++k) wih1[k] = w_ih1[grow*CC + k];
    #pragma unroll
    for (int k = 0; k < HH; ++k){
        whh1[k] = w_hh1[grow*HH + k];
        wih2[k] = w_ih2[grow*HH + k];
        whh2[k] = w_hh2[grow*HH + k];
    }
    const float b1 = b_ih1[grow] + b_hh1[grow];
    const float b2 = b_ih2[grow] + b_hh2[grow];

    const float* xb = x + (size_t)batch * (TT*FF);

    // sliding conv window rows t-1, t, t+1 (8 floats each; same for all lanes)
    float4 w0a = make_float4(0.f,0.f,0.f,0.f), w0b = w0a;
    float4 w1a = *(const float4*)(xb + 0);
    float4 w1b = *(const float4*)(xb + 4);
    float4 w2a = *(const float4*)(xb + 8);
    float4 w2b = *(const float4*)(xb + 12);

    float h1 = 0.f, c1 = 0.f, h2 = 0.f, c2 = 0.f;

    #pragma unroll 1
    for (int t = 0; t < TT; ++t){
        // prefetch row t+2
        float4 nxa = make_float4(0.f,0.f,0.f,0.f), nxb = nxa;
        if (t + 2 < TT){
            const float* p = xb + (t+2)*FF;
            nxa = *(const float4*)p;
            nxb = *(const float4*)(p + 4);
        }

        // ---- conv1d + relu, channel `ch` (two FMA chains) ----
        float a0 = cb, a1 = 0.f;
        a0 = fmaf(w0a.x, cw[0],  a0); a1 = fmaf(w1a.x, cw[1],  a1); a0 = fmaf(w2a.x, cw[2],  a0);
        a1 = fmaf(w0a.y, cw[3],  a1); a0 = fmaf(w1a.y, cw[4],  a0); a1 = fmaf(w2a.y, cw[5],  a1);
        a0 = fmaf(w0a.z, cw[6],  a0); a1 = fmaf(w1a.z, cw[7],  a1); a0 = fmaf(w2a.z, cw[8],  a0);
        a1 = fmaf(w0a.w, cw[9],  a1); a0 = fmaf(w1a.w, cw[10], a0); a1 = fmaf(w2a.w, cw[11], a1);
        a0 = fmaf(w0b.x, cw[12], a0); a1 = fmaf(w1b.x, cw[13], a1); a0 = fmaf(w2b.x, cw[14], a0);
        a1 = fmaf(w0b.y, cw[15], a1); a0 = fmaf(w1b.y, cw[16], a0); a1 = fmaf(w2b.y, cw[17], a1);
        a0 = fmaf(w0b.z, cw[18], a0); a1 = fmaf(w1b.z, cw[19], a1); a0 = fmaf(w2b.z, cw[20], a0);
        a1 = fmaf(w0b.w, cw[21], a1); a0 = fmaf(w1b.w, cw[22], a0); a1 = fmaf(w2b.w, cw[23], a1);
        const float y = fmaxf(a0 + a1, 0.f);      // valid in lanes 0..15

        // ---- layer 1: gate row `grow` = b1 + W_ih1[grow,:].y + W_hh1[grow,:].h1 ----
        float s0 = b1, s1 = 0.f;
        s0 = fmaf(rl(y,0),  wih1[0],  s0);  s1 = fmaf(rl(y,1),  wih1[1],  s1);
        s0 = fmaf(rl(y,2),  wih1[2],  s0);  s1 = fmaf(rl(y,3),  wih1[3],  s1);
        s0 = fmaf(rl(y,4),  wih1[4],  s0);  s1 = fmaf(rl(y,5),  wih1[5],  s1);
        s0 = fmaf(rl(y,6),  wih1[6],  s0);  s1 = fmaf(rl(y,7),  wih1[7],  s1);
        s0 = fmaf(rl(y,8),  wih1[8],  s0);  s1 = fmaf(rl(y,9),  wih1[9],  s1);
        s0 = fmaf(rl(y,10), wih1[10], s0);  s1 = fmaf(rl(y,11), wih1[11], s1);
        s0 = fmaf(rl(y,12), wih1[12], s0);  s1 = fmaf(rl(y,13), wih1[13], s1);
        s0 = fmaf(rl(y,14), wih1[14], s0);  s1 = fmaf(rl(y,15), wih1[15], s1);
        s0 = fmaf(rl(h1,0), whh1[0],  s0);  s1 = fmaf(rl(h1,1), whh1[1],  s1);
        s0 = fmaf(rl(h1,2), whh1[2],  s0);  s1 = fmaf(rl(h1,3), whh1[3],  s1);
        s0 = fmaf(rl(h1,4), whh1[4],  s0);  s1 = fmaf(rl(h1,5), whh1[5],  s1);
        s0 = fmaf(rl(h1,6), whh1[6],  s0);  s1 = fmaf(rl(h1,7), whh1[7],  s1);
        s0 = fmaf(rl(h1,8), whh1[8],  s0);  s1 = fmaf(rl(h1,9), whh1[9],  s1);
        const float g1 = s0 + s1;

        // branchless activation: rows 20..29 (g-gate) need tanh, others sigmoid
        // tanh(z) = 2*sig(2z) - 1
        const float z1  = isG ? (g1 + g1) : g1;
        const float sg1 = sigf(z1);
        const float act1 = isG ? fmaf(2.f, sg1, -1.f) : sg1;

        // collect unit u's four activations (srcs all < 40)
        const float ai1 = __shfl(act1, u,      64);
        const float af1 = __shfl(act1, u + 10, 64);
        const float ag1 = __shfl(act1, u + 20, 64);
        const float ao1 = __shfl(act1, u + 30, 64);
        c1 = fmaf(af1, c1, ai1 * ag1);
        h1 = ao1 * tanh_f(c1);                    // h1 for unit u, replicated in all lanes

        // ---- layer 2: gate row `grow` = b2 + W_ih2[grow,:].h1 + W_hh2[grow,:].h2 ----
        float d0 = b2, d1 = 0.f;
        d0 = fmaf(rl(h1,0), wih2[0], d0);  d1 = fmaf(rl(h1,1), wih2[1], d1);
        d0 = fmaf(rl(h1,2), wih2[2], d0);  d1 = fmaf(rl(h1,3), wih2[3], d1);
        d0 = fmaf(rl(h1,4), wih2[4], d0);  d1 = fmaf(rl(h1,5), wih2[5], d1);
        d0 = fmaf(rl(h1,6), wih2[6], d0);  d1 = fmaf(rl(h1,7), wih2[7], d1);
        d0 = fmaf(rl(h1,8), wih2[8], d0);  d1 = fmaf(rl(h1,9), wih2[9], d1);
        d0 = fmaf(rl(h2,0), whh2[0], d0);  d1 = fmaf(rl(h2,1), whh2[1], d1);
        d0 = fmaf(rl(h2,2), whh2[2], d0);  d1 = fmaf(rl(h2,3), whh2[3], d1);
        d0 = fmaf(rl(h2,4), whh2[4], d0);  d1 = fmaf(rl(h2,5), whh2[5], d1);
        d0 = fmaf(rl(h2,6), whh2[6], d0);  d1 = fmaf(rl(h2,7), whh2[7], d1);
        d0 = fmaf(rl(h2,8), whh2[8], d0);  d1 = fmaf(rl(h2,9), whh2[9], d1);
        const float g2 = d0 + d1;

        const float z2  = isG ? (g2 + g2) : g2;
        const float sg2 = sigf(z2);
        const float act2 = isG ? fmaf(2.f, sg2, -1.f) : sg2;

        const float ai2 = __shfl(act2, u,      64);
        const float af2 = __shfl(act2, u + 10, 64);
        const float ag2 = __shfl(act2, u + 20, 64);
        const float ao2 = __shfl(act2, u + 30, 64);
        c2 = fmaf(af2, c2, ai2 * ag2);
        h2 = ao2 * tanh_f(c2);                    // h2 for unit u, replicated

        // slide window
        w0a = w1a; w0b = w1b; w1a = w2a; w1b = w2b; w2a = nxa; w2b = nxb;
    }

    // final: sigmoid(h2 . lin_w + lin_b). lane j<10 holds h2_j (u=j for lanes<10)
    float part = (lane < HH) ? h2 * lin_w[lane] : 0.f;
    #pragma unroll
    for (int off = 8; off > 0; off >>= 1) part += __shfl_xor(part, off, 16);
    if (lane == 0) out[batch] = sigf(part + lin_b[0]);
}

extern "C" void kernel_launch(void* const* d_in, const int* in_sizes, int n_in,
                              void* d_out, int out_size, void* d_ws, size_t ws_size,
                              hipStream_t stream) {
    const float* x      = (const float*)d_in[0];
    const float* conv_w = (const float*)d_in[1];
    const float* conv_b = (const float*)d_in[2];
    const float* w_ih1  = (const float*)d_in[3];
    const float* w_hh1  = (const float*)d_in[4];
    const float* b_ih1  = (const float*)d_in[5];
    const float* b_hh1  = (const float*)d_in[6];
    const float* w_ih2  = (const float*)d_in[7];
    const float* w_hh2  = (const float*)d_in[8];
    const float* b_ih2  = (const float*)d_in[9];
    const float* b_hh2  = (const float*)d_in[10];
    const float* lin_w  = (const float*)d_in[11];
    const float* lin_b  = (const float*)d_in[12];
    float* out = (float*)d_out;

    // one wave per batch: 2048 waves -> 8 waves/CU = 2 per SIMD chip-wide
    lstm_fused<<<dim3(2048), dim3(64), 0, stream>>>(
        x, conv_w, conv_b, w_ih1, w_hh1, b_ih1, b_hh1,
        w_ih2, w_hh2, b_ih2, b_hh2, lin_w, lin_b, out);
}

// Round 5
// 282.142 us; speedup vs baseline: 1.6216x; 1.2038x over previous
//
#include <hip/hip_runtime.h>

#define TT 512
#define FF 8
#define CC 16
#define HH 10

__device__ __forceinline__ float rl(float v, int k){
    // wave-uniform broadcast: lane k -> SGPR, folds as scalar operand into v_fma
    return __int_as_float(__builtin_amdgcn_readlane(__float_as_int(v), k));
}
__device__ __forceinline__ float sigf(float z){
    return __builtin_amdgcn_rcpf(1.f + __expf(-z));
}
__device__ __forceinline__ float tanh_f(float z){
    return 1.f - 2.f * __builtin_amdgcn_rcpf(1.f + __expf(2.f * z));
}

// ONE wave per batch (2048 waves = 2/SIMD). lane<40 owns gate row grow=q*10+u.
// Software pipeline: iteration t computes layer2 for t-1 and layer1 for t —
// both consume h1(t-1) (shared readlane broadcasts hs0..hs9), so the two
// matvec->activation chains are independent and interleave in the SIMD.
#define CONV_Y(Y) do{                                                                              \
    float a0 = cb, a1 = 0.f;                                                                       \
    a0 = fmaf(w0a.x, cw[0],  a0); a1 = fmaf(w1a.x, cw[1],  a1); a0 = fmaf(w2a.x, cw[2],  a0);      \
    a1 = fmaf(w0a.y, cw[3],  a1); a0 = fmaf(w1a.y, cw[4],  a0); a1 = fmaf(w2a.y, cw[5],  a1);      \
    a0 = fmaf(w0a.z, cw[6],  a0); a1 = fmaf(w1a.z, cw[7],  a1); a0 = fmaf(w2a.z, cw[8],  a0);      \
    a1 = fmaf(w0a.w, cw[9],  a1); a0 = fmaf(w1a.w, cw[10], a0); a1 = fmaf(w2a.w, cw[11], a1);      \
    a0 = fmaf(w0b.x, cw[12], a0); a1 = fmaf(w1b.x, cw[13], a1); a0 = fmaf(w2b.x, cw[14], a0);      \
    a1 = fmaf(w0b.y, cw[15], a1); a0 = fmaf(w1b.y, cw[16], a0); a1 = fmaf(w2b.y, cw[17], a1);      \
    a0 = fmaf(w0b.z, cw[18], a0); a1 = fmaf(w1b.z, cw[19], a1); a0 = fmaf(w2b.z, cw[20], a0);      \
    a1 = fmaf(w0b.w, cw[21], a1); a0 = fmaf(w1b.w, cw[22], a0); a1 = fmaf(w2b.w, cw[23], a1);      \
    Y = fmaxf(a0 + a1, 0.f);                                                                       \
}while(0)

#define H1BCAST                                                                                    \
    const float hs0=rl(h1,0), hs1=rl(h1,1), hs2=rl(h1,2), hs3=rl(h1,3), hs4=rl(h1,4),              \
                hs5=rl(h1,5), hs6=rl(h1,6), hs7=rl(h1,7), hs8=rl(h1,8), hs9=rl(h1,9);

#define LAYER2 do{                                                                                 \
    float d0 = b2, d1 = 0.f;                                                                       \
    d0 = fmaf(hs0, wih2[0], d0);  d1 = fmaf(hs1, wih2[1], d1);                                     \
    d0 = fmaf(hs2, wih2[2], d0);  d1 = fmaf(hs3, wih2[3], d1);                                     \
    d0 = fmaf(hs4, wih2[4], d0);  d1 = fmaf(hs5, wih2[5], d1);                                     \
    d0 = fmaf(hs6, wih2[6], d0);  d1 = fmaf(hs7, wih2[7], d1);                                     \
    d0 = fmaf(hs8, wih2[8], d0);  d1 = fmaf(hs9, wih2[9], d1);                                     \
    d0 = fmaf(rl(h2,0), whh2[0], d0);  d1 = fmaf(rl(h2,1), whh2[1], d1);                           \
    d0 = fmaf(rl(h2,2), whh2[2], d0);  d1 = fmaf(rl(h2,3), whh2[3], d1);                           \
    d0 = fmaf(rl(h2,4), whh2[4], d0);  d1 = fmaf(rl(h2,5), whh2[5], d1);                           \
    d0 = fmaf(rl(h2,6), whh2[6], d0);  d1 = fmaf(rl(h2,7), whh2[7], d1);                           \
    d0 = fmaf(rl(h2,8), whh2[8], d0);  d1 = fmaf(rl(h2,9), whh2[9], d1);                           \
    const float g2  = d0 + d1;                                                                     \
    const float z2  = isG ? (g2 + g2) : g2;                                                        \
    const float sg2 = sigf(z2);                                                                    \
    const float act2 = isG ? fmaf(2.f, sg2, -1.f) : sg2;                                           \
    const float ai2 = __shfl(act2, u,      64);                                                    \
    const float af2 = __shfl(act2, u + 10, 64);                                                    \
    const float ag2 = __shfl(act2, u + 20, 64);                                                    \
    const float ao2 = __shfl(act2, u + 30, 64);                                                    \
    c2 = fmaf(af2, c2, ai2 * ag2);                                                                 \
    h2 = ao2 * tanh_f(c2);                                                                         \
}while(0)

#define LAYER1(YV) do{                                                                             \
    float s0 = b1, s1 = 0.f;                                                                       \
    s0 = fmaf(rl(YV,0),  wih1[0],  s0);  s1 = fmaf(rl(YV,1),  wih1[1],  s1);                       \
    s0 = fmaf(rl(YV,2),  wih1[2],  s0);  s1 = fmaf(rl(YV,3),  wih1[3],  s1);                       \
    s0 = fmaf(rl(YV,4),  wih1[4],  s0);  s1 = fmaf(rl(YV,5),  wih1[5],  s1);                       \
    s0 = fmaf(rl(YV,6),  wih1[6],  s0);  s1 = fmaf(rl(YV,7),  wih1[7],  s1);                       \
    s0 = fmaf(rl(YV,8),  wih1[8],  s0);  s1 = fmaf(rl(YV,9),  wih1[9],  s1);                       \
    s0 = fmaf(rl(YV,10), wih1[10], s0);  s1 = fmaf(rl(YV,11), wih1[11], s1);                       \
    s0 = fmaf(rl(YV,12), wih1[12], s0);  s1 = fmaf(rl(YV,13), wih1[13], s1);                       \
    s0 = fmaf(rl(YV,14), wih1[14], s0);  s1 = fmaf(rl(YV,15), wih1[15], s1);                       \
    s0 = fmaf(hs0, whh1[0], s0);  s1 = fmaf(hs1, whh1[1], s1);                                     \
    s0 = fmaf(hs2, whh1[2], s0);  s1 = fmaf(hs3, whh1[3], s1);                                     \
    s0 = fmaf(hs4, whh1[4], s0);  s1 = fmaf(hs5, whh1[5], s1);                                     \
    s0 = fmaf(hs6, whh1[6], s0);  s1 = fmaf(hs7, whh1[7], s1);                                     \
    s0 = fmaf(hs8, whh1[8], s0);  s1 = fmaf(hs9, whh1[9], s1);                                     \
    const float g1  = s0 + s1;                                                                     \
    const float z1  = isG ? (g1 + g1) : g1;                                                        \
    const float sg1 = sigf(z1);                                                                    \
    const float act1 = isG ? fmaf(2.f, sg1, -1.f) : sg1;                                           \
    const float ai1 = __shfl(act1, u,      64);                                                    \
    const float af1 = __shfl(act1, u + 10, 64);                                                    \
    const float ag1 = __shfl(act1, u + 20, 64);                                                    \
    const float ao1 = __shfl(act1, u + 30, 64);                                                    \
    c1 = fmaf(af1, c1, ai1 * ag1);                                                                 \
    h1n = ao1 * tanh_f(c1);                                                                        \
}while(0)

__global__ __launch_bounds__(64, 2)
void lstm_fused(const float* __restrict__ x,
                const float* __restrict__ conv_w, const float* __restrict__ conv_b,
                const float* __restrict__ w_ih1,  const float* __restrict__ w_hh1,
                const float* __restrict__ b_ih1,  const float* __restrict__ b_hh1,
                const float* __restrict__ w_ih2,  const float* __restrict__ w_hh2,
                const float* __restrict__ b_ih2,  const float* __restrict__ b_hh2,
                const float* __restrict__ lin_w,  const float* __restrict__ lin_b,
                float* __restrict__ out)
{
    const int lane  = threadIdx.x;
    const int batch = blockIdx.x;
    const int grow  = (lane < 40) ? lane : 39;      // gate row 0..39
    const int q     = grow / 10;                    // 0=i,1=f,2=g,3=o
    const int u     = grow - q * 10;                // hidden unit
    const int ch    = lane & 15;                    // conv channel
    const bool isG  = (q == 2);

    float cw[24];
    #pragma unroll
    for (int m = 0; m < 24; ++m) cw[m] = conv_w[ch*24 + m];
    const float cb = conv_b[ch];

    float wih1[CC], whh1[HH], wih2[HH], whh2[HH];
    #pragma unroll
    for (int k = 0; k < CC; ++k) wih1[k] = w_ih1[grow*CC + k];
    #pragma unroll
    for (int k = 0; k < HH; ++k){
        whh1[k] = w_hh1[grow*HH + k];
        wih2[k] = w_ih2[grow*HH + k];
        whh2[k] = w_hh2[grow*HH + k];
    }
    const float b1 = b_ih1[grow] + b_hh1[grow];
    const float b2 = b_ih2[grow] + b_hh2[grow];

    const float* xb = x + (size_t)batch * (TT*FF);

    float h1 = 0.f, c1 = 0.f, h2 = 0.f, c2 = 0.f, h1n;

    // window rows t-1, t, t+1
    float4 w0a = make_float4(0.f,0.f,0.f,0.f), w0b = w0a;
    float4 w1a = *(const float4*)(xb + 0);
    float4 w1b = *(const float4*)(xb + 4);
    float4 w2a = *(const float4*)(xb + 8);
    float4 w2b = *(const float4*)(xb + 12);

    // ---- prologue: t=0, layer1 only ----
    {
        float y0; CONV_Y(y0);
        H1BCAST;                 // h1(-1)=0
        LAYER1(y0);
        h1 = h1n;
    }
    // slide to window for t=1 (rows 0,1,2)
    w0a = w1a; w0b = w1b; w1a = w2a; w1b = w2b;
    w2a = *(const float4*)(xb + 16);
    w2b = *(const float4*)(xb + 20);

    // ---- main loop: iteration t does layer2(t-1) || layer1(t) ----
    #pragma unroll 3
    for (int t = 1; t < TT; ++t){
        float4 nxa = make_float4(0.f,0.f,0.f,0.f), nxb = nxa;
        if (t + 2 < TT){
            const float* p = xb + (t+2)*FF;
            nxa = *(const float4*)p;
            nxb = *(const float4*)(p + 4);
        }
        float y; CONV_Y(y);
        {
            H1BCAST;             // broadcasts of h1(t-1), shared by both layers
            LAYER2;              // h2(t-1) from h1(t-1), h2(t-2)  — chain A
            LAYER1(y);           // h1(t)   from y(t),   h1(t-1)  — chain B
        }
        h1 = h1n;
        w0a = w1a; w0b = w1b; w1a = w2a; w1b = w2b; w2a = nxa; w2b = nxb;
    }

    // ---- epilogue: layer2 for t=TT-1 ----
    {
        H1BCAST;
        LAYER2;
    }

    // final: sigmoid(h2 . lin_w + lin_b); lanes 0..9 hold h2[0..9]
    float part = (lane < HH) ? h2 * lin_w[lane] : 0.f;
    #pragma unroll
    for (int off = 8; off > 0; off >>= 1) part += __shfl_xor(part, off, 16);
    if (lane == 0) out[batch] = sigf(part + lin_b[0]);
}

extern "C" void kernel_launch(void* const* d_in, const int* in_sizes, int n_in,
                              void* d_out, int out_size, void* d_ws, size_t ws_size,
                              hipStream_t stream) {
    const float* x      = (const float*)d_in[0];
    const float* conv_w = (const float*)d_in[1];
    const float* conv_b = (const float*)d_in[2];
    const float* w_ih1  = (const float*)d_in[3];
    const float* w_hh1  = (const float*)d_in[4];
    const float* b_ih1  = (const float*)d_in[5];
    const float* b_hh1  = (const float*)d_in[6];
    const float* w_ih2  = (const float*)d_in[7];
    const float* w_hh2  = (const float*)d_in[8];
    const float* b_ih2  = (const float*)d_in[9];
    const float* b_hh2  = (const float*)d_in[10];
    const float* lin_w  = (const float*)d_in[11];
    const float* lin_b  = (const float*)d_in[12];
    float* out = (float*)d_out;

    // one wave per batch: 2048 waves -> 2 per SIMD chip-wide
    lstm_fused<<<dim3(2048), dim3(64), 0, stream>>>(
        x, conv_w, conv_b, w_ih1, w_hh1, b_ih1, b_hh1,
        w_ih2, w_hh2, b_ih2, b_hh2, lin_w, lin_b, out);
}